// Round 1
// baseline (2332.233 us; speedup 1.0000x reference)
//
#include <hip/hip_runtime.h>
#include <math.h>

// DotProductAttention: B=64, L=1024, D=64, fp32.
// out = softmax(mask(Q K^T / 8)) V, mask: key >= valid_len[b] -> -1e6.
// exp(-1e6 - m) == 0 in fp32, so masked keys can be skipped exactly.

constexpr int Bn = 64;
constexpr int Ln = 1024;
constexpr int Dn = 64;
constexpr float SCALE = 0.125f;  // 1/sqrt(64)

__global__ __launch_bounds__(256) void attn_fp32(
    const float* __restrict__ Q, const float* __restrict__ K,
    const float* __restrict__ V, const int* __restrict__ VL,
    float* __restrict__ O)
{
    // One wave per query row; 4 rows per block.
    __shared__ float pbuf[4][Ln];   // 16 KiB: per-wave score/prob row

    const int w = threadIdx.x >> 6;   // wave in block: 0..3
    const int l = threadIdx.x & 63;   // lane
    const int blk = blockIdx.x;
    const int b = blk >> 8;                       // blk / (L/4)
    const int q = ((blk & 255) << 2) | w;         // query row
    const int qrow = __builtin_amdgcn_readfirstlane(q);  // wave-uniform

    const int valid = VL[b];

    const size_t bbase = (size_t)b * Ln * Dn;
    const float* Kp = K + bbase;
    const float* Vp = V + bbase;
    const float* Qp = Q + bbase + (size_t)qrow * Dn;

    // Q row: wave-uniform pointer -> scalar loads (s_load), held uniform.
    float4 qv[16];
    #pragma unroll
    for (int j = 0; j < 16; ++j)
        qv[j] = reinterpret_cast<const float4*>(Qp)[j];

    // ---- Phase 1: scores. lane l handles keys l, l+64, ..., l+960. ----
    float m = -INFINITY;
    #pragma unroll 2
    for (int i = 0; i < 16; ++i) {
        const int k = (i << 6) | l;
        const float4* kr = reinterpret_cast<const float4*>(Kp + (size_t)k * Dn);
        float acc = 0.f;
        #pragma unroll
        for (int j = 0; j < 16; ++j) {
            const float4 kv = kr[j];
            acc += qv[j].x * kv.x;
            acc += qv[j].y * kv.y;
            acc += qv[j].z * kv.z;
            acc += qv[j].w * kv.w;
        }
        const float sc = acc * SCALE;
        pbuf[w][k] = sc;
        if (k < valid) m = fmaxf(m, sc);
    }

    // wave max-reduce (64 lanes)
    #pragma unroll
    for (int off = 32; off > 0; off >>= 1)
        m = fmaxf(m, __shfl_xor(m, off, 64));

    __syncthreads();

    // ---- Phase 2: exp + sum; store p back to LDS. ----
    float sum = 0.f;
    #pragma unroll 2
    for (int i = 0; i < 16; ++i) {
        const int k = (i << 6) | l;
        const float sc = pbuf[w][k];
        const float p = (k < valid) ? __expf(sc - m) : 0.f;
        pbuf[w][k] = p;
        sum += p;
    }
    #pragma unroll
    for (int off = 32; off > 0; off >>= 1)
        sum += __shfl_xor(sum, off, 64);

    __syncthreads();

    // ---- Phase 3: out[d=l] = (1/sum) * sum_k p[k] * V[k][d]. ----
    // p read: LDS same-address broadcast (free). V read: coalesced.
    float acc = 0.f;
    const int kmax = (valid + 3) & ~3;   // p==0 beyond valid; kmax <= 1024
    #pragma unroll 2
    for (int k = 0; k < kmax; k += 4) {
        const float4 p4 = *reinterpret_cast<const float4*>(&pbuf[w][k]);
        acc += p4.x * Vp[(size_t)(k + 0) * Dn + l];
        acc += p4.y * Vp[(size_t)(k + 1) * Dn + l];
        acc += p4.z * Vp[(size_t)(k + 2) * Dn + l];
        acc += p4.w * Vp[(size_t)(k + 3) * Dn + l];
    }

    O[(bbase + (size_t)qrow * Dn) + l] = acc * (1.0f / sum);
}

extern "C" void kernel_launch(void* const* d_in, const int* in_sizes, int n_in,
                              void* d_out, int out_size, void* d_ws, size_t ws_size,
                              hipStream_t stream) {
    const float* Q = (const float*)d_in[0];
    const float* K = (const float*)d_in[1];
    const float* V = (const float*)d_in[2];
    const int* VL = (const int*)d_in[3];
    float* O = (float*)d_out;

    const int blocks = Bn * (Ln / 4);   // 16384 blocks, 4 q-rows each
    attn_fp32<<<blocks, 256, 0, stream>>>(Q, K, V, VL, O);
}

// Round 2
// 145.699 us; speedup vs baseline: 16.0073x; 16.0073x over previous
//
#include <hip/hip_runtime.h>
#include <math.h>

// DotProductAttention B=64, L=1024, D=64 fp32 -> bf16 MFMA flash attention.
// out = softmax(mask(Q K^T / 8)) V ; key >= valid_len[b] -> -1e6 -> exp==0 exactly,
// so masked keys are skipped (valid_len is batch-uniform -> skip whole KV tiles).

typedef __attribute__((ext_vector_type(4))) float f32x4;
typedef __attribute__((ext_vector_type(8))) short bf16x8;
typedef __attribute__((ext_vector_type(8))) unsigned short u16x8;

constexpr int Bn = 64, Ln = 1024, Dn = 64;
constexpr float SCALE = 0.125f;  // 1/sqrt(64)

__device__ inline unsigned short f2bf(float x) {  // round-to-nearest-even
    unsigned int u = __float_as_uint(x);
    return (unsigned short)((u + 0x7fffu + ((u >> 16) & 1u)) >> 16);
}

// ---- fp32 -> bf16 flat convert (n multiple of 2048*8) ----
__global__ __launch_bounds__(256) void conv_bf16(const float* __restrict__ src,
                                                 unsigned short* __restrict__ dst, int n)
{
    int i = (blockIdx.x * 256 + threadIdx.x) * 8;
    if (i >= n) return;
    float4 a = *reinterpret_cast<const float4*>(src + i);
    float4 b = *reinterpret_cast<const float4*>(src + i + 4);
    u16x8 o;
    o[0] = f2bf(a.x); o[1] = f2bf(a.y); o[2] = f2bf(a.z); o[3] = f2bf(a.w);
    o[4] = f2bf(b.x); o[5] = f2bf(b.y); o[6] = f2bf(b.z); o[7] = f2bf(b.w);
    *reinterpret_cast<u16x8*>(dst + i) = o;
}

// ---- V [B][L][D] f32 -> Vt [B][D][L] bf16 (tiled transpose) ----
__global__ __launch_bounds__(256) void transp_v(const float* __restrict__ V,
                                                unsigned short* __restrict__ Vt)
{
    __shared__ float tile[64][65];
    const int b = blockIdx.x >> 4, kt = blockIdx.x & 15;
    const float* src = V + ((size_t)b * Ln + kt * 64) * Dn;
    const int tr = threadIdx.x >> 4;   // 0..15
    const int tc = threadIdx.x & 15;   // 0..15
    #pragma unroll
    for (int i = 0; i < 4; ++i) {
        int k = tr + i * 16;
        float4 v = *reinterpret_cast<const float4*>(src + (size_t)k * Dn + tc * 4);
        tile[k][tc * 4 + 0] = v.x; tile[k][tc * 4 + 1] = v.y;
        tile[k][tc * 4 + 2] = v.z; tile[k][tc * 4 + 3] = v.w;
    }
    __syncthreads();
    unsigned short* dst = Vt + (size_t)b * Dn * Ln + kt * 64;
    #pragma unroll
    for (int i = 0; i < 4; ++i) {
        int d = tr + i * 16;
        int k0 = tc * 4;
        ushort4 o;
        o.x = f2bf(tile[k0 + 0][d]); o.y = f2bf(tile[k0 + 1][d]);
        o.z = f2bf(tile[k0 + 2][d]); o.w = f2bf(tile[k0 + 3][d]);
        *reinterpret_cast<ushort4*>(dst + (size_t)d * Ln + k0) = o;
    }
}

// ---- flash attention ----
// grid: 1024 blocks = (b, qtile of 64 rows); 4 waves, each owns 16 q-rows.
// mfma_f32_16x16x32_bf16. A-frag: lane l holds A[m=l&15][k=(l>>4)*8+j].
// B-frag: B[k=(l>>4)*8+j][n=l&15]. D: D[m=(l>>4)*4+j][n=l&15]  (m89-verified).
__global__ __launch_bounds__(256) void flash_attn(
    const unsigned short* __restrict__ Qb,  // [B][L][D] bf16
    const unsigned short* __restrict__ Kb,  // [B][L][D] bf16
    const unsigned short* __restrict__ Vtb, // [B][D][L] bf16
    const int* __restrict__ VL,
    float* __restrict__ O)
{
    __shared__ unsigned short kls[64 * 64];      // K tile [kv][d], swizzled
    __shared__ unsigned short vls[64 * 64];      // V tile [d][kv], swizzled
    __shared__ unsigned short plds[4][16 * 64];  // per-wave P [q][kv], swizzled

    const int tid = threadIdx.x;
    const int w = tid >> 6, l = tid & 63;
    const int lg = l >> 4;     // lane group 0..3
    const int ln = l & 15;
    const int b = blockIdx.x >> 4;
    const int qt = blockIdx.x & 15;
    const int qbase = qt * 64 + w * 16;
    const int valid = VL[b];
    const int nkt = (valid + 63) >> 6;   // KV tiles beyond valid contribute 0 exactly

    // Q fragments (held in registers for the whole kernel)
    const unsigned short* Qrow = Qb + ((size_t)b * Ln + qbase + ln) * Dn;
    const bf16x8 aq0 = *reinterpret_cast<const bf16x8*>(Qrow + lg * 8);
    const bf16x8 aq1 = *reinterpret_cast<const bf16x8*>(Qrow + 32 + lg * 8);

    f32x4 acc[4] = {{0.f,0.f,0.f,0.f},{0.f,0.f,0.f,0.f},{0.f,0.f,0.f,0.f},{0.f,0.f,0.f,0.f}};
    float mrow[4] = {-1e30f, -1e30f, -1e30f, -1e30f};
    float lrow[4] = {0.f, 0.f, 0.f, 0.f};

    const unsigned short* Kbase = Kb  + (size_t)b * Ln * Dn;
    const unsigned short* Vbase = Vtb + (size_t)b * Dn * Ln;
    unsigned short* pw = plds[w];

    for (int kt = 0; kt < nkt; ++kt) {
        __syncthreads();   // prior iter's LDS reads complete before restage
        // ---- stage K,V tiles: 512 16B-chunks each, 2 per thread ----
        #pragma unroll
        for (int i = 0; i < 2; ++i) {
            int cid = tid + i * 256;
            int r = cid >> 3, c = cid & 7;
            int off = ((r * 128 + c * 16) ^ ((r & 7) << 4)) >> 1;   // ushort idx
            u16x8 kv = *reinterpret_cast<const u16x8*>(Kbase + (size_t)(kt * 64 + r) * Dn + c * 8);
            *reinterpret_cast<u16x8*>(kls + off) = kv;
            u16x8 vv = *reinterpret_cast<const u16x8*>(Vbase + (size_t)r * Ln + kt * 64 + c * 8);
            *reinterpret_cast<u16x8*>(vls + off) = vv;
        }
        __syncthreads();

        // ---- QK^T: S[16q x 64k] per wave ----
        f32x4 st[4] = {{0.f,0.f,0.f,0.f},{0.f,0.f,0.f,0.f},{0.f,0.f,0.f,0.f},{0.f,0.f,0.f,0.f}};
        #pragma unroll
        for (int t = 0; t < 4; ++t) {
            #pragma unroll
            for (int s = 0; s < 2; ++s) {
                int r = 16 * t + ln;
                int off = ((r * 128 + (lg * 8 + 32 * s) * 2) ^ ((r & 7) << 4)) >> 1;
                bf16x8 bk = *reinterpret_cast<const bf16x8*>(kls + off);
                st[t] = __builtin_amdgcn_mfma_f32_16x16x32_bf16(s == 0 ? aq0 : aq1, bk, st[t], 0, 0, 0);
            }
        }

        // ---- mask + online softmax (row = lg*4+j, cols = 16t+ln) ----
        const int kbase = kt * 64;
        float sc[4][4];
        #pragma unroll
        for (int t = 0; t < 4; ++t) {
            bool msk = (kbase + 16 * t + ln) >= valid;
            #pragma unroll
            for (int j = 0; j < 4; ++j)
                sc[t][j] = msk ? -1e30f : st[t][j] * SCALE;
        }
        float mnew[4], rescale[4];
        #pragma unroll
        for (int j = 0; j < 4; ++j) {
            float mx = fmaxf(fmaxf(sc[0][j], sc[1][j]), fmaxf(sc[2][j], sc[3][j]));
            #pragma unroll
            for (int off = 8; off >= 1; off >>= 1) mx = fmaxf(mx, __shfl_xor(mx, off, 64));
            mnew[j] = fmaxf(mrow[j], mx);
            rescale[j] = __expf(mrow[j] - mnew[j]);
            mrow[j] = mnew[j];
        }
        #pragma unroll
        for (int j = 0; j < 4; ++j) {
            float rs = 0.f;
            const int q = lg * 4 + j;
            #pragma unroll
            for (int t = 0; t < 4; ++t) {
                float p = __expf(sc[t][j] - mnew[j]);   // masked -> exp(-huge) == 0
                rs += p;
                int col = 16 * t + ln;
                int off = ((q * 128 + col * 2) ^ ((q & 7) << 4)) >> 1;
                pw[off] = f2bf(p);
            }
            #pragma unroll
            for (int off = 8; off >= 1; off >>= 1) rs += __shfl_xor(rs, off, 64);
            lrow[j] = lrow[j] * rescale[j] + rs;
            #pragma unroll
            for (int t = 0; t < 4; ++t) acc[t][j] *= rescale[j];
        }
        __syncthreads();   // P write -> P read (cross-lane within wave; keep safe)

        // ---- PV: acc[16q x 64d] += P[16q x 64k] * V[64k x 64d] ----
        #pragma unroll
        for (int s = 0; s < 2; ++s) {
            int poff = ((ln * 128 + (lg * 8 + 32 * s) * 2) ^ ((ln & 7) << 4)) >> 1;
            bf16x8 pa = *reinterpret_cast<const bf16x8*>(pw + poff);
            #pragma unroll
            for (int t = 0; t < 4; ++t) {
                int r = 16 * t + ln;
                int voff = ((r * 128 + (lg * 8 + 32 * s) * 2) ^ ((r & 7) << 4)) >> 1;
                bf16x8 bv = *reinterpret_cast<const bf16x8*>(vls + voff);
                acc[t] = __builtin_amdgcn_mfma_f32_16x16x32_bf16(pa, bv, acc[t], 0, 0, 0);
            }
        }
    }

    // ---- epilogue: O[q][d] = acc / l ----
    float inv[4];
    #pragma unroll
    for (int j = 0; j < 4; ++j) inv[j] = 1.0f / lrow[j];
    float* Orow = O + ((size_t)b * Ln + qbase) * Dn;
    #pragma unroll
    for (int t = 0; t < 4; ++t) {
        #pragma unroll
        for (int j = 0; j < 4; ++j) {
            int q = lg * 4 + j;
            int d = 16 * t + ln;
            Orow[(size_t)q * Dn + d] = acc[t][j] * inv[j];
        }
    }
}

extern "C" void kernel_launch(void* const* d_in, const int* in_sizes, int n_in,
                              void* d_out, int out_size, void* d_ws, size_t ws_size,
                              hipStream_t stream) {
    const float* Q = (const float*)d_in[0];
    const float* K = (const float*)d_in[1];
    const float* V = (const float*)d_in[2];
    const int* VL = (const int*)d_in[3];
    float* O = (float*)d_out;

    const int n = Bn * Ln * Dn;                       // 4,194,304 per tensor
    unsigned short* Qb  = (unsigned short*)d_ws;      // 8 MB
    unsigned short* Kbb = Qb + (size_t)n;             // 8 MB
    unsigned short* Vtb = Kbb + (size_t)n;            // 8 MB (24 MB total ws)

    conv_bf16<<<n / 8 / 256, 256, 0, stream>>>(Q, Qb, n);
    conv_bf16<<<n / 8 / 256, 256, 0, stream>>>(K, Kbb, n);
    transp_v<<<Bn * 16, 256, 0, stream>>>(V, Vtb);
    flash_attn<<<Bn * 16, 256, 0, stream>>>(Qb, Kbb, Vtb, VL, O);
}

// Round 4
// 137.700 us; speedup vs baseline: 16.9371x; 1.0581x over previous
//
#include <hip/hip_runtime.h>
#include <math.h>

// Fused flash attention, B=64, L=1024, D=64, fp32 in/out.
// out = softmax(mask(Q K^T / 8)) V ; key >= valid_len[b] -> -1e6 -> exp == 0 exactly,
// so KV tiles >= valid are skipped (exact). Softmax runs in exp2 domain with
// 1/sqrt(d)*log2(e) folded into the Q->bf16 conversion.

typedef __attribute__((ext_vector_type(4))) float f32x4;
typedef __attribute__((ext_vector_type(8))) short bf16x8;
typedef __attribute__((ext_vector_type(8))) unsigned short u16x8;

constexpr int Bn = 64, Ln = 1024, Dn = 64;
constexpr float QSCALE = 0.125f * 1.44269504088896340736f;  // 1/sqrt(64) * log2(e)
constexpr float DEFER_THR = 10.0f;   // log2 domain: deferred p bounded by 2^10

__device__ inline unsigned short f2bf(float x) {  // round-to-nearest-even
    unsigned int u = __float_as_uint(x);
    return (unsigned short)((u + 0x7fffu + ((u >> 16) & 1u)) >> 16);
}

__global__ __launch_bounds__(256) void flash_attn(
    const float* __restrict__ Q, const float* __restrict__ K,
    const float* __restrict__ V, const int* __restrict__ VL,
    float* __restrict__ O)
{
    __shared__ unsigned short kls[64 * 64];      // K tile [kv][d] bf16, XOR-swizzled
    __shared__ unsigned short vls[64 * 64];      // V tile [d][kv] bf16, XOR-swizzled
    __shared__ unsigned short plds[4][16 * 64];  // per-wave P [q][kv], XOR-swizzled

    const int tid = threadIdx.x;
    const int w = tid >> 6, l = tid & 63;
    const int lg = l >> 4, ln = l & 15;
    const int b = blockIdx.x >> 4;
    const int qt = blockIdx.x & 15;
    const int qbase = qt * 64 + w * 16;
    const int valid = VL[b];
    const int nkt = (valid + 63) >> 6;   // tiles beyond valid contribute exactly 0

    const float* Kbase = K + (size_t)b * Ln * Dn;
    const float* Vbase = V + (size_t)b * Ln * Dn;

    // ---- Q A-fragments: f32 load, fold QSCALE, convert to bf16 ----
    bf16x8 aq0, aq1;
    {
        const f32x4* qp = reinterpret_cast<const f32x4*>(Q + ((size_t)b * Ln + qbase + ln) * Dn);
        f32x4 q0 = qp[lg * 2], q1 = qp[lg * 2 + 1], q2 = qp[8 + lg * 2], q3 = qp[8 + lg * 2 + 1];
        #pragma unroll
        for (int j = 0; j < 4; ++j) {
            aq0[j]     = (short)f2bf(q0[j] * QSCALE);
            aq0[j + 4] = (short)f2bf(q1[j] * QSCALE);
            aq1[j]     = (short)f2bf(q2[j] * QSCALE);
            aq1[j + 4] = (short)f2bf(q3[j] * QSCALE);
        }
    }

    // staging thread mapping
    const int kr = tid >> 2, kc = (tid & 3) * 16;  // K: row kr, cols kc..kc+15
    const int vd = l, vk0 = w * 16;                // V: d = lane, k = vk0..vk0+15

    // prefetch registers (T14: issue early, write late)
    f32x4 kpre[4];
    float vpre[16];
    {   // prologue: tile 0
        const f32x4* kp = reinterpret_cast<const f32x4*>(Kbase + (size_t)kr * Dn + kc);
        #pragma unroll
        for (int i = 0; i < 4; ++i) kpre[i] = kp[i];
        const float* vp = Vbase + (size_t)vk0 * Dn + vd;
        #pragma unroll
        for (int i = 0; i < 16; ++i) vpre[i] = vp[(size_t)i * Dn];
    }

    f32x4 acc[4] = {{0.f,0.f,0.f,0.f},{0.f,0.f,0.f,0.f},{0.f,0.f,0.f,0.f},{0.f,0.f,0.f,0.f}};
    float mrow[4] = {-1e30f, -1e30f, -1e30f, -1e30f};
    float lrow[4] = {0.f, 0.f, 0.f, 0.f};
    unsigned short* pw = plds[w];
    char* klsb = reinterpret_cast<char*>(kls);
    char* vlsb = reinterpret_cast<char*>(vls);
    char* pwb  = reinterpret_cast<char*>(pw);

    for (int kt = 0; kt < nkt; ++kt) {
        __syncthreads();   // prior tile's LDS reads complete
        // ---- staged regs -> LDS (convert f32->bf16) ----
        {
            u16x8 c0, c1;
            #pragma unroll
            for (int j = 0; j < 4; ++j) {
                c0[j]     = f2bf(kpre[0][j]);  c0[j + 4] = f2bf(kpre[1][j]);
                c1[j]     = f2bf(kpre[2][j]);  c1[j + 4] = f2bf(kpre[3][j]);
            }
            const int kb = kr * 128 + kc * 2, ksw = (kr & 7) << 4;
            *reinterpret_cast<u16x8*>(klsb + ((kb)      ^ ksw)) = c0;
            *reinterpret_cast<u16x8*>(klsb + ((kb + 16) ^ ksw)) = c1;
            u16x8 v0, v1;
            #pragma unroll
            for (int j = 0; j < 8; ++j) { v0[j] = f2bf(vpre[j]); v1[j] = f2bf(vpre[j + 8]); }
            const int vb = vd * 128 + vk0 * 2, vsw = (vd & 7) << 4;
            *reinterpret_cast<u16x8*>(vlsb + ((vb)      ^ vsw)) = v0;
            *reinterpret_cast<u16x8*>(vlsb + ((vb + 16) ^ vsw)) = v1;
        }
        __syncthreads();

        // ---- issue next tile's global loads (consumed next iteration) ----
        if (kt + 1 < nkt) {
            const f32x4* kp = reinterpret_cast<const f32x4*>(Kbase + (size_t)((kt + 1) * 64 + kr) * Dn + kc);
            #pragma unroll
            for (int i = 0; i < 4; ++i) kpre[i] = kp[i];
            const float* vp = Vbase + (size_t)((kt + 1) * 64 + vk0) * Dn + vd;
            #pragma unroll
            for (int i = 0; i < 16; ++i) vpre[i] = vp[(size_t)i * Dn];
        }

        // ---- QK^T: S[16q x 64k] (already in exp2-scaled domain) ----
        f32x4 st[4] = {{0.f,0.f,0.f,0.f},{0.f,0.f,0.f,0.f},{0.f,0.f,0.f,0.f},{0.f,0.f,0.f,0.f}};
        #pragma unroll
        for (int t = 0; t < 4; ++t) {
            const int r = 16 * t + ln, rsw = (r & 7) << 4;
            bf16x8 bk0 = *reinterpret_cast<const bf16x8*>(klsb + ((r * 128 + lg * 16)      ^ rsw));
            st[t] = __builtin_amdgcn_mfma_f32_16x16x32_bf16(aq0, bk0, st[t], 0, 0, 0);
            bf16x8 bk1 = *reinterpret_cast<const bf16x8*>(klsb + ((r * 128 + lg * 16 + 64) ^ rsw));
            st[t] = __builtin_amdgcn_mfma_f32_16x16x32_bf16(aq1, bk1, st[t], 0, 0, 0);
        }

        // ---- mask (only the partial last tile; wave-uniform branch) ----
        const int kbase = kt * 64;
        if (kbase + 64 > valid) {
            #pragma unroll
            for (int t = 0; t < 4; ++t) {
                const bool msk = (kbase + 16 * t + ln) >= valid;
                #pragma unroll
                for (int j = 0; j < 4; ++j) if (msk) st[t][j] = -1e30f;
            }
        }

        // ---- online softmax with deferred rescale (T13) ----
        float mx[4];
        #pragma unroll
        for (int j = 0; j < 4; ++j) {
            float m0 = fmaxf(fmaxf(st[0][j], st[1][j]), fmaxf(st[2][j], st[3][j]));
            #pragma unroll
            for (int off = 8; off >= 1; off >>= 1) m0 = fmaxf(m0, __shfl_xor(m0, off, 64));
            mx[j] = m0;
        }
        const float g = fmaxf(fmaxf(mx[0] - mrow[0], mx[1] - mrow[1]),
                              fmaxf(mx[2] - mrow[2], mx[3] - mrow[3]));
        if (__any(g > DEFER_THR)) {
            #pragma unroll
            for (int j = 0; j < 4; ++j) {
                const float mn = fmaxf(mrow[j], mx[j]);
                const float rs = exp2f(mrow[j] - mn);
                mrow[j] = mn;
                lrow[j] *= rs;
                #pragma unroll
                for (int t = 0; t < 4; ++t) acc[t][j] *= rs;
            }
        }
        #pragma unroll
        for (int j = 0; j < 4; ++j) {
            const int q = lg * 4 + j, qsw = (q & 7) << 4;
            float rs = 0.f;
            #pragma unroll
            for (int t = 0; t < 4; ++t) {
                const float p = exp2f(st[t][j] - mrow[j]);   // masked -> exp2(-huge) == 0
                rs += p;
                const int col = 16 * t + ln;
                *reinterpret_cast<unsigned short*>(pwb + ((q * 128 + col * 2) ^ qsw)) = f2bf(p);
            }
            #pragma unroll
            for (int off = 8; off >= 1; off >>= 1) rs += __shfl_xor(rs, off, 64);
            lrow[j] += rs;
        }
        // no __syncthreads: plds is per-wave; intra-wave DS ops are in-order and
        // the compiler inserts lgkmcnt before the aliasing reads below.

        // ---- PV: acc[16q x 64d] += P[16q x 64k] * V[64k x 64d] ----
        #pragma unroll
        for (int s = 0; s < 2; ++s) {
            bf16x8 pa = *reinterpret_cast<const bf16x8*>(
                pwb + ((ln * 128 + lg * 16 + 64 * s) ^ ((ln & 7) << 4)));
            #pragma unroll
            for (int t = 0; t < 4; ++t) {
                const int r = 16 * t + ln, rsw = (r & 7) << 4;
                bf16x8 bv = *reinterpret_cast<const bf16x8*>(vlsb + ((r * 128 + lg * 16 + 64 * s) ^ rsw));
                acc[t] = __builtin_amdgcn_mfma_f32_16x16x32_bf16(pa, bv, acc[t], 0, 0, 0);
            }
        }
    }

    // ---- epilogue ----
    float inv[4];
    #pragma unroll
    for (int j = 0; j < 4; ++j) inv[j] = 1.0f / lrow[j];
    float* Orow = O + ((size_t)b * Ln + qbase) * Dn;
    #pragma unroll
    for (int t = 0; t < 4; ++t) {
        #pragma unroll
        for (int j = 0; j < 4; ++j) {
            const int q = lg * 4 + j;
            const int d = 16 * t + ln;
            Orow[(size_t)q * Dn + d] = acc[t][j] * inv[j];
        }
    }
}

extern "C" void kernel_launch(void* const* d_in, const int* in_sizes, int n_in,
                              void* d_out, int out_size, void* d_ws, size_t ws_size,
                              hipStream_t stream) {
    const float* Q = (const float*)d_in[0];
    const float* K = (const float*)d_in[1];
    const float* V = (const float*)d_in[2];
    const int* VL = (const int*)d_in[3];
    float* O = (float*)d_out;
    flash_attn<<<Bn * 16, 256, 0, stream>>>(Q, K, V, VL, O);
}